// Round 1
// baseline (285.172 us; speedup 1.0000x reference)
//
#include <hip/hip_runtime.h>
#include <math.h>

#define NQ 4
#define NL 2

// ---------------------------------------------------------------------------
// Kernel 1: precompute A = Re(M^dagger D M), where M = product of all Rot/CZ
// gates (depends only on qweights), D = diag(sign of qubit-0 bit).
// Then <Z_0> per sample = psi^T A psi with psi the real RY-embedding vector.
// ---------------------------------------------------------------------------
__global__ void qnn_precompute_A(const float* __restrict__ qw, float* __restrict__ A)
{
    __shared__ float Mre[16][16]; // [column j][basis b]
    __shared__ float Mim[16][16];
    int j = threadIdx.x;
    if (j < 16) {
        float re[16], im[16];
        for (int b = 0; b < 16; ++b) { re[b] = (b == j) ? 1.f : 0.f; im[b] = 0.f; }
        for (int l = 0; l < NL; ++l) {
            for (int i = 0; i < NQ; ++i) {
                float phi   = qw[(l*NQ + i)*3 + 0];
                float theta = qw[(l*NQ + i)*3 + 1];
                float omega = qw[(l*NQ + i)*3 + 2];
                float ct, st; sincosf(0.5f*theta, &st, &ct);
                float ap = 0.5f*(phi + omega);
                float am = 0.5f*(phi - omega);
                float cap, sap, cam, sam;
                sincosf(ap, &sap, &cap);
                sincosf(am, &sam, &cam);
                // Rot(phi,theta,omega) = RZ(omega)RY(theta)RZ(phi):
                // u00 = e^{-i ap} ct ; u01 = -e^{+i am} st
                // u10 = e^{-i am} st ; u11 = e^{+i ap} ct
                float u00r =  cap*ct, u00i = -sap*ct;
                float u01r = -cam*st, u01i = -sam*st;
                float u10r =  cam*st, u10i = -sam*st;
                float u11r =  cap*ct, u11i =  sap*ct;
                int mask = 1 << (3 - i);   // wire i lives on bit (3-i)
                for (int b = 0; b < 16; ++b) {
                    if (b & mask) continue;
                    int b1 = b | mask;
                    float a0r = re[b],  a0i = im[b];
                    float a1r = re[b1], a1i = im[b1];
                    re[b]  = u00r*a0r - u00i*a0i + u01r*a1r - u01i*a1i;
                    im[b]  = u00r*a0i + u00i*a0r + u01r*a1i + u01i*a1r;
                    re[b1] = u10r*a0r - u10i*a0i + u11r*a1r - u11i*a1i;
                    im[b1] = u10r*a0i + u10i*a0r + u11r*a1i + u11i*a1r;
                }
            }
            // CZ chain on wire pairs (0,1),(1,2),(2,3) -> bit masks 0xC,0x6,0x3
            for (int b = 0; b < 16; ++b) {
                float sgn = 1.f;
                if ((b & 0xC) == 0xC) sgn = -sgn;
                if ((b & 0x6) == 0x6) sgn = -sgn;
                if ((b & 0x3) == 0x3) sgn = -sgn;
                re[b] *= sgn; im[b] *= sgn;
            }
        }
        for (int b = 0; b < 16; ++b) { Mre[j][b] = re[b]; Mim[j][b] = im[b]; }
    }
    __syncthreads();
    if (j < 16) {
        for (int k = 0; k < 16; ++k) {
            float s = 0.f;
            for (int b = 0; b < 16; ++b) {
                float sg = (b & 8) ? -1.f : 1.f;   // bit 3 == wire 0
                s += sg * (Mre[j][b]*Mre[k][b] + Mim[j][b]*Mim[k][b]);
            }
            A[j*16 + k] = s;
        }
    }
}

// ---------------------------------------------------------------------------
// Kernel 2: one thread per sample. fp32 throughout (abs threshold 1.48e-2,
// fp32 error ~1e-5). Weight accesses are wave-uniform -> scalar loads / L1.
// ---------------------------------------------------------------------------
__global__ __launch_bounds__(256) void qnn_main(
    const float* __restrict__ text, const float* __restrict__ image,
    const float* __restrict__ tW1, const float* __restrict__ tb1,
    const float* __restrict__ tW2, const float* __restrict__ tb2,
    const float* __restrict__ iW1, const float* __restrict__ ib1,
    const float* __restrict__ iW2, const float* __restrict__ ib2,
    const float* __restrict__ A,
    const float* __restrict__ cW1, const float* __restrict__ cb1,
    const float* __restrict__ cW2, const float* __restrict__ cb2,
    float* __restrict__ out, int B)
{
    int b = blockIdx.x * blockDim.x + threadIdx.x;
    if (b >= B) return;

    // ---- text MLP: [16] -> relu[32] -> [4]
    float t[16];
    const float4* t4 = (const float4*)(text + (size_t)b * 16);
    #pragma unroll
    for (int i = 0; i < 4; ++i) {
        float4 v = t4[i];
        t[4*i] = v.x; t[4*i+1] = v.y; t[4*i+2] = v.z; t[4*i+3] = v.w;
    }

    float h1[32];
    #pragma unroll
    for (int jj = 0; jj < 32; ++jj) h1[jj] = tb1[jj];
    #pragma unroll 4
    for (int k = 0; k < 16; ++k) {
        float v = t[k];
        const float* w = tW1 + k*32;
        #pragma unroll
        for (int jj = 0; jj < 32; ++jj) h1[jj] = fmaf(v, w[jj], h1[jj]);
    }
    float tf[4];
    #pragma unroll
    for (int o = 0; o < 4; ++o) tf[o] = tb2[o];
    #pragma unroll
    for (int jj = 0; jj < 32; ++jj) {
        float r = fmaxf(h1[jj], 0.f);
        const float* w2 = tW2 + jj*4;
        #pragma unroll
        for (int o = 0; o < 4; ++o) tf[o] = fmaf(r, w2[o], tf[o]);
    }

    // ---- image MLP: [48] -> relu[64] -> [4]  (hidden in two halves of 32)
    float im[48];
    const float4* i4 = (const float4*)(image + (size_t)b * 48);
    #pragma unroll
    for (int i = 0; i < 12; ++i) {
        float4 v = i4[i];
        im[4*i] = v.x; im[4*i+1] = v.y; im[4*i+2] = v.z; im[4*i+3] = v.w;
    }

    float imf[4];
    #pragma unroll
    for (int o = 0; o < 4; ++o) imf[o] = ib2[o];
    #pragma unroll
    for (int half = 0; half < 2; ++half) {
        float h2[32];
        #pragma unroll
        for (int jj = 0; jj < 32; ++jj) h2[jj] = ib1[half*32 + jj];
        #pragma unroll 4
        for (int k = 0; k < 48; ++k) {
            float v = im[k];
            const float* w = iW1 + k*64 + half*32;
            #pragma unroll
            for (int jj = 0; jj < 32; ++jj) h2[jj] = fmaf(v, w[jj], h2[jj]);
        }
        #pragma unroll
        for (int jj = 0; jj < 32; ++jj) {
            float r = fmaxf(h2[jj], 0.f);
            const float* w2 = iW2 + (half*32 + jj)*4;
            #pragma unroll
            for (int o = 0; o < 4; ++o) imf[o] = fmaf(r, w2[o], imf[o]);
        }
    }

    // ---- quantum expectation via precomputed quadratic form
    // feats = (tf+imf)*0.5 ; angle = feats*0.5  => f = (tf+imf)*0.25
    float c[4], s[4];
    #pragma unroll
    for (int i = 0; i < 4; ++i) {
        float f = (tf[i] + imf[i]) * 0.25f;
        __sincosf(f, &s[i], &c[i]);
    }
    // psi_b = prod over wires; bit3=wire0, bit2=wire1, bit1=wire2, bit0=wire3
    float p01[4] = { c[0]*c[1], c[0]*s[1], s[0]*c[1], s[0]*s[1] };
    float p23[4] = { c[2]*c[3], c[2]*s[3], s[2]*c[3], s[2]*s[3] };
    float psi[16];
    #pragma unroll
    for (int x = 0; x < 4; ++x)
        #pragma unroll
        for (int y = 0; y < 4; ++y)
            psi[x*4+y] = p01[x] * p23[y];

    float q = 0.f;
    #pragma unroll
    for (int jj = 0; jj < 16; ++jj) {
        float row = 0.f;
        #pragma unroll
        for (int k = 0; k < 16; ++k) row = fmaf(A[jj*16+k], psi[k], row);
        q = fmaf(psi[jj], row, q);
    }

    // ---- classifier head: h = relu(q*cW1 + cb1) [16]; out = h@cW2 + cb2 [2]
    float o0 = cb2[0], o1 = cb2[1];
    #pragma unroll
    for (int jj = 0; jj < 16; ++jj) {
        float h = fmaxf(fmaf(q, cW1[jj], cb1[jj]), 0.f);
        o0 = fmaf(h, cW2[jj*2+0], o0);
        o1 = fmaf(h, cW2[jj*2+1], o1);
    }
    float2* o2 = (float2*)out;
    o2[b] = make_float2(o0, o1);
}

extern "C" void kernel_launch(void* const* d_in, const int* in_sizes, int n_in,
                              void* d_out, int out_size, void* d_ws, size_t ws_size,
                              hipStream_t stream)
{
    const float* text  = (const float*)d_in[0];
    const float* image = (const float*)d_in[1];
    const float* tW1   = (const float*)d_in[2];
    const float* tb1   = (const float*)d_in[3];
    const float* tW2   = (const float*)d_in[4];
    const float* tb2   = (const float*)d_in[5];
    const float* iW1   = (const float*)d_in[6];
    const float* ib1   = (const float*)d_in[7];
    const float* iW2   = (const float*)d_in[8];
    const float* ib2   = (const float*)d_in[9];
    const float* qw    = (const float*)d_in[10];
    const float* cW1   = (const float*)d_in[11];
    const float* cb1   = (const float*)d_in[12];
    const float* cW2   = (const float*)d_in[13];
    const float* cb2   = (const float*)d_in[14];

    float* A = (float*)d_ws;          // 256 floats
    int B = in_sizes[0] / 16;

    qnn_precompute_A<<<1, 64, 0, stream>>>(qw, A);

    int block = 256;
    int grid = (B + block - 1) / block;
    qnn_main<<<grid, block, 0, stream>>>(
        text, image, tW1, tb1, tW2, tb2, iW1, ib1, iW2, ib2,
        A, cW1, cb1, cW2, cb2, (float*)d_out, B);
}

// Round 2
// 257.638 us; speedup vs baseline: 1.1069x; 1.1069x over previous
//
#include <hip/hip_runtime.h>
#include <math.h>

#define NQ 4
#define NL 2

// ---------------------------------------------------------------------------
// Kernel 1: precompute A = Re(M^dagger D M), where M = product of all Rot/CZ
// gates (depends only on qweights), D = diag(sign of qubit-0 bit).
// Then <Z_0> per sample = psi^T A psi with psi the real RY-embedding vector.
// Phase 1: 16 threads simulate the 16 basis columns. Phase 2: 256 threads
// compute one A[j][k] entry each (16-term dot). ~1-2 us total.
// ---------------------------------------------------------------------------
__global__ void qnn_precompute_A(const float* __restrict__ qw, float* __restrict__ A)
{
    __shared__ float Mre[16][16]; // [column j][basis b]
    __shared__ float Mim[16][16];
    int t = threadIdx.x;
    if (t < 16) {
        int j = t;
        float re[16], im[16];
        for (int b = 0; b < 16; ++b) { re[b] = (b == j) ? 1.f : 0.f; im[b] = 0.f; }
        for (int l = 0; l < NL; ++l) {
            for (int i = 0; i < NQ; ++i) {
                float phi   = qw[(l*NQ + i)*3 + 0];
                float theta = qw[(l*NQ + i)*3 + 1];
                float omega = qw[(l*NQ + i)*3 + 2];
                float ct, st; sincosf(0.5f*theta, &st, &ct);
                float ap = 0.5f*(phi + omega);
                float am = 0.5f*(phi - omega);
                float cap, sap, cam, sam;
                sincosf(ap, &sap, &cap);
                sincosf(am, &sam, &cam);
                // Rot = RZ(omega)RY(theta)RZ(phi):
                // u00 = e^{-i ap} ct ; u01 = -e^{+i am} st
                // u10 = e^{-i am} st ; u11 = e^{+i ap} ct
                float u00r =  cap*ct, u00i = -sap*ct;
                float u01r = -cam*st, u01i = -sam*st;
                float u10r =  cam*st, u10i = -sam*st;
                float u11r =  cap*ct, u11i =  sap*ct;
                int mask = 1 << (3 - i);   // wire i lives on bit (3-i)
                for (int b = 0; b < 16; ++b) {
                    if (b & mask) continue;
                    int b1 = b | mask;
                    float a0r = re[b],  a0i = im[b];
                    float a1r = re[b1], a1i = im[b1];
                    re[b]  = u00r*a0r - u00i*a0i + u01r*a1r - u01i*a1i;
                    im[b]  = u00r*a0i + u00i*a0r + u01r*a1i + u01i*a1r;
                    re[b1] = u10r*a0r - u10i*a0i + u11r*a1r - u11i*a1i;
                    im[b1] = u10r*a0i + u10i*a0r + u11r*a1i + u11i*a1r;
                }
            }
            // CZ chain on wire pairs (0,1),(1,2),(2,3) -> bit masks 0xC,0x6,0x3
            for (int b = 0; b < 16; ++b) {
                float sgn = 1.f;
                if ((b & 0xC) == 0xC) sgn = -sgn;
                if ((b & 0x6) == 0x6) sgn = -sgn;
                if ((b & 0x3) == 0x3) sgn = -sgn;
                re[b] *= sgn; im[b] *= sgn;
            }
        }
        for (int b = 0; b < 16; ++b) { Mre[j][b] = re[b]; Mim[j][b] = im[b]; }
    }
    __syncthreads();
    {
        int j = t >> 4, k = t & 15;
        float s = 0.f;
        #pragma unroll
        for (int b = 0; b < 16; ++b) {
            float sg = (b & 8) ? -1.f : 1.f;   // bit 3 == wire 0
            s += sg * (Mre[j][b]*Mre[k][b] + Mim[j][b]*Mim[k][b]);
        }
        A[j*16 + k] = s;
    }
}

// ---------------------------------------------------------------------------
// Kernel 2: one thread per sample, fp32 VALU. Restructured to avoid scratch
// spills: sequential phases, inputs streamed (no big staging arrays), peak
// live ~80 VGPRs. __launch_bounds__(256,4): 128-VGPR budget, 16 waves/CU.
// ---------------------------------------------------------------------------
__global__ __launch_bounds__(256, 4) void qnn_main(
    const float* __restrict__ text, const float* __restrict__ image,
    const float* __restrict__ tW1, const float* __restrict__ tb1,
    const float* __restrict__ tW2, const float* __restrict__ tb2,
    const float* __restrict__ iW1, const float* __restrict__ ib1,
    const float* __restrict__ iW2, const float* __restrict__ ib2,
    const float* __restrict__ A,
    const float* __restrict__ cW1, const float* __restrict__ cb1,
    const float* __restrict__ cW2, const float* __restrict__ cb2,
    float* __restrict__ out, int B)
{
    int b = blockIdx.x * blockDim.x + threadIdx.x;
    if (b >= B) return;

    // ---- image MLP: [48] -> relu[64] -> [4], h2[64] accumulators, streamed input
    float h2[64];
    #pragma unroll
    for (int j = 0; j < 64; ++j) h2[j] = ib1[j];
    {
        const float4* i4 = (const float4*)(image + (size_t)b * 48);
        #pragma unroll 2
        for (int k4 = 0; k4 < 12; ++k4) {
            float4 v = i4[k4];
            const float* w = iW1 + k4 * 4 * 64;
            #pragma unroll
            for (int j = 0; j < 64; ++j) h2[j] = fmaf(v.x, w[j],       h2[j]);
            #pragma unroll
            for (int j = 0; j < 64; ++j) h2[j] = fmaf(v.y, w[64 + j],  h2[j]);
            #pragma unroll
            for (int j = 0; j < 64; ++j) h2[j] = fmaf(v.z, w[128 + j], h2[j]);
            #pragma unroll
            for (int j = 0; j < 64; ++j) h2[j] = fmaf(v.w, w[192 + j], h2[j]);
        }
    }
    float imf[4];
    #pragma unroll
    for (int o = 0; o < 4; ++o) imf[o] = ib2[o];
    #pragma unroll
    for (int j = 0; j < 64; ++j) {
        float r = fmaxf(h2[j], 0.f);
        const float* w2 = iW2 + j * 4;
        #pragma unroll
        for (int o = 0; o < 4; ++o) imf[o] = fmaf(r, w2[o], imf[o]);
    }

    // ---- text MLP: [16] -> relu[32] -> [4], h1[32] accumulators, streamed input
    float h1[32];
    #pragma unroll
    for (int j = 0; j < 32; ++j) h1[j] = tb1[j];
    {
        const float4* t4 = (const float4*)(text + (size_t)b * 16);
        #pragma unroll
        for (int k4 = 0; k4 < 4; ++k4) {
            float4 v = t4[k4];
            const float* w = tW1 + k4 * 4 * 32;
            #pragma unroll
            for (int j = 0; j < 32; ++j) h1[j] = fmaf(v.x, w[j],      h1[j]);
            #pragma unroll
            for (int j = 0; j < 32; ++j) h1[j] = fmaf(v.y, w[32 + j], h1[j]);
            #pragma unroll
            for (int j = 0; j < 32; ++j) h1[j] = fmaf(v.z, w[64 + j], h1[j]);
            #pragma unroll
            for (int j = 0; j < 32; ++j) h1[j] = fmaf(v.w, w[96 + j], h1[j]);
        }
    }
    float tf[4];
    #pragma unroll
    for (int o = 0; o < 4; ++o) tf[o] = tb2[o];
    #pragma unroll
    for (int j = 0; j < 32; ++j) {
        float r = fmaxf(h1[j], 0.f);
        const float* w2 = tW2 + j * 4;
        #pragma unroll
        for (int o = 0; o < 4; ++o) tf[o] = fmaf(r, w2[o], tf[o]);
    }

    // ---- quantum expectation via precomputed quadratic form
    // feats = (tf+imf)*0.5 ; angle = feats*0.5  => f = (tf+imf)*0.25
    float c[4], s[4];
    #pragma unroll
    for (int i = 0; i < 4; ++i) {
        float f = (tf[i] + imf[i]) * 0.25f;
        __sincosf(f, &s[i], &c[i]);
    }
    // psi_b = prod over wires; bit3=wire0, bit2=wire1, bit1=wire2, bit0=wire3
    float p01[4] = { c[0]*c[1], c[0]*s[1], s[0]*c[1], s[0]*s[1] };
    float p23[4] = { c[2]*c[3], c[2]*s[3], s[2]*c[3], s[2]*s[3] };
    float psi[16];
    #pragma unroll
    for (int x = 0; x < 4; ++x)
        #pragma unroll
        for (int y = 0; y < 4; ++y)
            psi[x*4+y] = p01[x] * p23[y];

    float q = 0.f;
    #pragma unroll
    for (int j = 0; j < 16; ++j) {
        float row = 0.f;
        #pragma unroll
        for (int k = 0; k < 16; ++k) row = fmaf(A[j*16+k], psi[k], row);
        q = fmaf(psi[j], row, q);
    }

    // ---- classifier head: h = relu(q*cW1 + cb1) [16]; out = h@cW2 + cb2 [2]
    float o0 = cb2[0], o1 = cb2[1];
    #pragma unroll
    for (int j = 0; j < 16; ++j) {
        float h = fmaxf(fmaf(q, cW1[j], cb1[j]), 0.f);
        o0 = fmaf(h, cW2[j*2+0], o0);
        o1 = fmaf(h, cW2[j*2+1], o1);
    }
    float2* o2 = (float2*)out;
    o2[b] = make_float2(o0, o1);
}

extern "C" void kernel_launch(void* const* d_in, const int* in_sizes, int n_in,
                              void* d_out, int out_size, void* d_ws, size_t ws_size,
                              hipStream_t stream)
{
    const float* text  = (const float*)d_in[0];
    const float* image = (const float*)d_in[1];
    const float* tW1   = (const float*)d_in[2];
    const float* tb1   = (const float*)d_in[3];
    const float* tW2   = (const float*)d_in[4];
    const float* tb2   = (const float*)d_in[5];
    const float* iW1   = (const float*)d_in[6];
    const float* ib1   = (const float*)d_in[7];
    const float* iW2   = (const float*)d_in[8];
    const float* ib2   = (const float*)d_in[9];
    const float* qw    = (const float*)d_in[10];
    const float* cW1   = (const float*)d_in[11];
    const float* cb1   = (const float*)d_in[12];
    const float* cW2   = (const float*)d_in[13];
    const float* cb2   = (const float*)d_in[14];

    float* A = (float*)d_ws;          // 256 floats
    int B = in_sizes[0] / 16;

    qnn_precompute_A<<<1, 256, 0, stream>>>(qw, A);

    int block = 256;
    int grid = (B + block - 1) / block;
    qnn_main<<<grid, block, 0, stream>>>(
        text, image, tW1, tb1, tW2, tb2, iW1, ib1, iW2, ib2,
        A, cW1, cb1, cW2, cb2, (float*)d_out, B);
}